// Round 10
// baseline (127.923 us; speedup 1.0000x reference)
//
#include <hip/hip_runtime.h>

typedef _Float16 half8 __attribute__((ext_vector_type(8)));
typedef _Float16 half4_t __attribute__((ext_vector_type(4)));
typedef __fp16 fp16x2 __attribute__((ext_vector_type(2)));
typedef float float4_t __attribute__((ext_vector_type(4)));
typedef float float2_t __attribute__((ext_vector_type(2)));
typedef float float16_t __attribute__((ext_vector_type(16)));

#define SB 64            // samples per block
#define NT 512           // 8 waves: mt = wv&3 (32 rows), sg = wv>>2 (32 samples)
#define RS (SB * 8)      // chunk-row stride in fp16 elems (512)

// ws fp16 element offsets
#define OFF_W1   0       // [4 mt][2 kc][2 half][32 m][8 j], k>=6 zeroed, x2log2e
#define OFF_W21  4096    // 128x128: [4 mt][8 kc][2 half][32 m][8 j] = 16384 each
#define OFF_W22  20480
#define OFF_WM1  36864
#define OFF_WM2  53248
#define OFF_W4A  69632   // L4 16x16x32 A-frags: chain0=w31, chain1=w32 x(-log2e)
#define OFF_BIAS 73728   // fp32[640]: b1..bm2, x2log2e
#define WS_HELEMS 73728

#define SCL_TANH 2.8853900817779268f   // 2*log2(e)
#define SCL_SIG  -1.4426950408889634f  // -log2(e)

__device__ __forceinline__ float tanh_pre(float a) {   // input pre-scaled by 2log2e
  float e = __builtin_amdgcn_exp2f(a);
  return fmaf(-2.f, __builtin_amdgcn_rcpf(1.f + e), 1.f);
}
__device__ __forceinline__ half4_t pack4(float v0, float v1, float v2, float v3) {
  fp16x2 lo = __builtin_amdgcn_cvt_pkrtz(v0, v1);
  fp16x2 hi = __builtin_amdgcn_cvt_pkrtz(v2, v3);
  half4_t h;
  h[0] = (_Float16)lo[0]; h[1] = (_Float16)lo[1];
  h[2] = (_Float16)hi[0]; h[3] = (_Float16)hi[1];
  return h;
}

__global__ void prepack(const float* __restrict__ w1, const float* __restrict__ w21,
                        const float* __restrict__ w22, const float* __restrict__ wm1,
                        const float* __restrict__ wm2, const float* __restrict__ w31,
                        const float* __restrict__ w32, const float* __restrict__ b1,
                        const float* __restrict__ b21, const float* __restrict__ b22,
                        const float* __restrict__ bm1, const float* __restrict__ bm2,
                        _Float16* __restrict__ ws) {
  const int stride = gridDim.x * blockDim.x;
  for (int i = blockIdx.x * blockDim.x + threadIdx.x; i < WS_HELEMS; i += stride) {
    float v;
    if (i < OFF_W21) {                       // W1: 32x32 A-frag layout, KC=2
      int j = i & 7, c = i >> 3, m32 = c & 31, t1 = c >> 5;
      int half = t1 & 1, t2 = t1 >> 1, kc = t2 & 1, mt = t2 >> 1;
      int row = mt * 32 + m32, k = kc * 16 + half * 8 + j;
      v = (k < 6) ? w1[row * 6 + k] * SCL_TANH : 0.f;
    } else if (i < OFF_W4A) {                // four 128x128, 32x32 A-frags, KC=8
      int t = i - OFF_W21;
      int m = t >> 14; t &= 16383;
      const float* src = (m == 0) ? w21 : (m == 1) ? w22 : (m == 2) ? wm1 : wm2;
      int j = t & 7, c = t >> 3, m32 = c & 31, t1 = c >> 5;
      int half = t1 & 1, t2 = t1 >> 1, kc = t2 & 7, mt = t2 >> 3;
      v = src[(mt * 32 + m32) * 128 + kc * 16 + half * 8 + j] * SCL_TANH;
    } else if (i < OFF_BIAS) {               // L4 16x16x32 A-frags, 2 chains
      int t = i - OFF_W4A;
      int j = t & 7, r = t >> 3, l16 = r & 15, q = r >> 4;
      int cc = q & 15, chain = q >> 4;
      int k = cc * 8 + j, m = l16;
      if (chain == 0) v = (m < 3) ? w31[m * 128 + k] : 0.f;
      else            v = (m < 2) ? w32[m * 128 + k] * SCL_SIG : 0.f;
    } else { v = 0.f; }
    ws[i] = (_Float16)v;
  }
  float* bws = (float*)(ws + OFF_BIAS);
  for (int i = blockIdx.x * blockDim.x + threadIdx.x; i < 640; i += stride) {
    int layer = i >> 7, idx = i & 127;
    const float* src = (layer == 0) ? b1 : (layer == 1) ? b21
                     : (layer == 2) ? b22 : (layer == 3) ? bm1 : bm2;
    bws[i] = src[idx] * SCL_TANH;
  }
}

template <int KC>
__device__ __forceinline__ void loadA32(half8* A, const _Float16* base,
                                        int mt, int half, int m32) {
#pragma unroll
  for (int kc = 0; kc < KC; ++kc)
    A[kc] = *(const half8*)(base + (((mt * KC + kc) * 2 + half) * 32 + m32) * 8);
}

// bias -> acc init in 32x32 C layout: row=(reg&3)+8*(reg>>2)+4*half (+mt*32)
__device__ __forceinline__ float16_t bias_init32(const float* biasL, int mt, int half) {
  float16_t a;
#pragma unroll
  for (int G = 0; G < 4; ++G) {
    float4_t bv = *(const float4_t*)(biasL + mt * 32 + G * 8 + 4 * half);
#pragma unroll
    for (int i2 = 0; i2 < 4; ++i2) a[G * 4 + i2] = bv[i2];
  }
  return a;
}

// tanh + pack + chunk-major LDS store of a 32x32 C tile
__device__ __forceinline__ void store32(float16_t acc, _Float16* outB,
                                        int mt, int half, int sOff) {
#pragma unroll
  for (int G = 0; G < 4; ++G) {
    half4_t h = pack4(tanh_pre(acc[G * 4 + 0]), tanh_pre(acc[G * 4 + 1]),
                      tanh_pre(acc[G * 4 + 2]), tanh_pre(acc[G * 4 + 3]));
    *(half4_t*)(outB + (mt * 4 + G) * RS + sOff * 8 + 4 * half) = h;
  }
}

// one 32-row x 32-sample layer pass (K=128) via 32x32x16 MFMA
__device__ __forceinline__ void pass32(const half8* A, const float* biasL,
                                       const _Float16* inB, _Float16* outB,
                                       int mt, int half, int sOff) {
  float16_t acc = bias_init32(biasL, mt, half);
#pragma unroll
  for (int kc = 0; kc < 8; ++kc) {
    half8 b = *(const half8*)(inB + (kc * 2 + half) * RS + sOff * 8);
    acc = __builtin_amdgcn_mfma_f32_32x32x16_f16(A[kc], b, acc, 0, 0, 0);
  }
  store32(acc, outB, mt, half, sOff);
}

// LDS 3 x 16KB = 48KB -> 3 blocks/CU. launch_bounds(512,4): VGPR cap 128
// (r8 lesson: cap 85 spills; actual use here ~110-125).
__global__ __launch_bounds__(NT, 4) void bnet_main(
    const float* __restrict__ x, const float* __restrict__ meang,
    const float* __restrict__ stdg, const float* __restrict__ b31,
    const float* __restrict__ b32, const _Float16* __restrict__ ws,
    float* __restrict__ out) {
  __shared__ __align__(16) _Float16 bufH[SB * 128];
  __shared__ __align__(16) _Float16 bufA[SB * 128];
  __shared__ __align__(16) _Float16 bufB[SB * 128];

  const int tid = threadIdx.x;
  const int wv = tid >> 6;
  const int lane = tid & 63;
  const int half = lane >> 5;
  const int m32 = lane & 31;
  const int mt = wv & 3;             // 32-row m-tile
  const int sg = wv >> 2;            // 32-sample group
  const int sOff = sg * 32 + m32;    // sample index within block (B n / C col)
  const int quad = lane >> 4;        // for L4 16x16 path
  const int l16 = lane & 15;
  const int s0 = blockIdx.x * SB;
  const float* biasF = (const float*)(ws + OFF_BIAS);

  // ---- prologue: A-frags for fused L21/L22 ----
  half8 A21[8], A22[8];
  loadA32<8>(A21, ws + OFF_W21, mt, half, m32);
  loadA32<8>(A22, ws + OFF_W22, mt, half, m32);

  // ---- L1: kc=0 only (k>=6 zero); B built from global x ----
  {
    float16_t acc = bias_init32(biasF, mt, half);
    half8 v;
#pragma unroll
    for (int j = 0; j < 8; ++j) v[j] = (_Float16)0.f;
    if (half == 0) {
      const float* xp = x + (size_t)(s0 + sOff) * 6;
      float2_t e0 = *(const float2_t*)(xp);
      float2_t e1 = *(const float2_t*)(xp + 2);
      float2_t e2 = *(const float2_t*)(xp + 4);
      v[0] = (_Float16)e0[0]; v[1] = (_Float16)e0[1];
      v[2] = (_Float16)e1[0]; v[3] = (_Float16)e1[1];
      v[4] = (_Float16)e2[0]; v[5] = (_Float16)e2[1];
    }
    half8 A1 = *(const half8*)(ws + OFF_W1 + ((mt * 2 * 2 + half) * 32 + m32) * 8);
    acc = __builtin_amdgcn_mfma_f32_32x32x16_f16(A1, v, acc, 0, 0, 0);
    store32(acc, bufH, mt, half, sOff);
  }
  __syncthreads();                                   // b1

  // ---- fused L21+L22: shared B-reads of bufH, two acc chains ----
  {
    float16_t a1 = bias_init32(biasF + 128, mt, half);
    float16_t a2 = bias_init32(biasF + 256, mt, half);
#pragma unroll
    for (int kc = 0; kc < 8; ++kc) {
      half8 b = *(const half8*)(bufH + (kc * 2 + half) * RS + sOff * 8);
      a1 = __builtin_amdgcn_mfma_f32_32x32x16_f16(A21[kc], b, a1, 0, 0, 0);
      a2 = __builtin_amdgcn_mfma_f32_32x32x16_f16(A22[kc], b, a2, 0, 0, 0);
    }
    store32(a1, bufA, mt, half, sOff);               // x21
    store32(a2, bufB, mt, half, sOff);               // x22
  }
  half8 AM1[8];                                      // prefetch M1 across b2
  loadA32<8>(AM1, ws + OFF_WM1, mt, half, m32);
  __syncthreads();                                   // b2

  pass32(AM1, biasF + 384, bufA, bufH, mt, half, sOff);   // xm1: A -> H
  half8 AM2[8];                                      // prefetch M2 across b3
  loadA32<8>(AM2, ws + OFF_WM2, mt, half, m32);
  half8 A4[2][4];                                    // prefetch L4 (waves 0-3)
  if (wv < 4) {
#pragma unroll
    for (int c = 0; c < 2; ++c)
#pragma unroll
      for (int kk = 0; kk < 4; ++kk)
        A4[c][kk] = *(const half8*)(ws + OFF_W4A +
                                    ((c * 16 + kk * 4 + quad) * 16 + l16) * 8);
  }
  __syncthreads();                                   // b3

  pass32(AM2, biasF + 512, bufB, bufA, mt, half, sOff);   // xm2: B -> A
  // L4 chain0: reads xm1 (bufH, stable since b3). Waves 0-3, 16x16x32.
  float4_t c0 = (float4_t){0.f, 0.f, 0.f, 0.f};
  if (wv < 4) {
    if (quad == 0) { c0[0] = b31[0]; c0[1] = b31[1]; c0[2] = b31[2]; }
    const int nt = wv;
#pragma unroll
    for (int kk = 0; kk < 4; ++kk) {
      half8 bh = *(const half8*)(bufH + (kk * 4 + quad) * RS + (nt * 16 + l16) * 8);
      c0 = __builtin_amdgcn_mfma_f32_16x16x32_f16(A4[0][kk], bh, c0, 0, 0, 0);
    }
  }
  __syncthreads();                                   // b4

  // ---- L4 chain1 + QP epilogue: waves 0-3 ----
  if (wv < 4) {
    const int nt = wv;
    float4_t c1 = (float4_t){0.f, 0.f, 0.f, 0.f};
    if (quad == 0) { c1[0] = b32[0] * SCL_SIG; c1[1] = b32[1] * SCL_SIG; }
#pragma unroll
    for (int kk = 0; kk < 4; ++kk) {
      half8 bc = *(const half8*)(bufA + (kk * 4 + quad) * RS + (nt * 16 + l16) * 8);
      c1 = __builtin_amdgcn_mfma_f32_16x16x32_f16(A4[1][kk], bc, c1, 0, 0, 0);
    }
    if (quad == 0) {
      const int s = nt * 16 + l16;
      float u0 = -c0[0];
      float u1 = -c0[1];
      float u2 = -c0[2];
      float p0 = 4.f * __builtin_amdgcn_rcpf(1.f + __builtin_amdgcn_exp2f(c1[0]));
      float p1 = 4.f * __builtin_amdgcn_rcpf(1.f + __builtin_amdgcn_exp2f(c1[1]));
      const float m0 = meang[0], m1 = meang[1], m2 = meang[2];
      const float m3 = meang[3], m4 = meang[4], m5 = meang[5];
      const float sd0 = stdg[0], sd1 = stdg[1], sd2 = stdg[2];
      const float sd3 = stdg[3], sd4 = stdg[4], sd5 = stdg[5];
      const float* xp = x + (size_t)(s0 + s) * 6;
      float2_t e0 = *(const float2_t*)(xp);
      float2_t e1 = *(const float2_t*)(xp + 2);
      float2_t e2 = *(const float2_t*)(xp + 4);
      float px = e0[0] * sd0 + m0, vx = e0[1] * sd1 + m1;
      float py = e1[0] * sd2 + m2, vy = e1[1] * sd3 + m3;
      float pz = e2[0] * sd4 + m4, vz = e2[1] * sd5 + m5;
      float dx = px - 10.f, dy = py - 10.f, dz = pz - 9.f;
      float dx2 = dx * dx, dy2 = dy * dy, dz2 = dz * dz;
      float dx3 = dx2 * dx, dy3 = dy2 * dy, dz3 = dz2 * dz;
      float barrier = dx3 * dx + dy3 * dy + dz3 * dz - 2401.f;  // R^4
      float bdot = 4.f * (dx3 * vx + dy3 * vy + dz3 * vz);
      float Lf2b = 12.f * (dx2 * vx * vx + dy2 * vy * vy + dz2 * vz * vz);
      float g0 = -4.f * dx3, g1 = -4.f * dy3, g2 = -4.f * dz3;
      float hv = Lf2b + (p0 + p1) * bdot + p0 * p1 * barrier;
      float Gu = g0 * u0 + g1 * u1 + g2 * u2;
      float GG = g0 * g0 + g1 * g1 + g2 * g2;
      float lam = fmaxf(Gu - hv, 0.f) / GG;
      float* op = out + (size_t)(s0 + s) * 3;
      op[0] = u0 - lam * g0;
      op[1] = u1 - lam * g1;
      op[2] = u2 - lam * g2;
    }
  }
}

extern "C" void kernel_launch(void* const* d_in, const int* in_sizes, int n_in,
                              void* d_out, int out_size, void* d_ws, size_t ws_size,
                              hipStream_t stream) {
  const float* x    = (const float*)d_in[0];
  const float* mean = (const float*)d_in[1];
  const float* stdv = (const float*)d_in[2];
  const float* w1   = (const float*)d_in[3];
  const float* b1   = (const float*)d_in[4];
  const float* w21  = (const float*)d_in[5];
  const float* b21  = (const float*)d_in[6];
  const float* w22  = (const float*)d_in[7];
  const float* b22  = (const float*)d_in[8];
  const float* wm1  = (const float*)d_in[9];
  const float* bm1  = (const float*)d_in[10];
  const float* wm2  = (const float*)d_in[11];
  const float* bm2  = (const float*)d_in[12];
  const float* w31  = (const float*)d_in[13];
  const float* b31  = (const float*)d_in[14];
  const float* w32  = (const float*)d_in[15];
  const float* b32  = (const float*)d_in[16];
  _Float16* ws = (_Float16*)d_ws;
  float* out = (float*)d_out;
  const int batch = in_sizes[0] / 6;

  hipLaunchKernelGGL(prepack, dim3(96), dim3(256), 0, stream,
                     w1, w21, w22, wm1, wm2, w31, w32,
                     b1, b21, b22, bm1, bm2, ws);
  hipLaunchKernelGGL(bnet_main, dim3(batch / SB), dim3(NT), 0, stream,
                     x, mean, stdv, b31, b32, (const _Float16*)ws, out);
}